// Round 3
// baseline (433.097 us; speedup 1.0000x reference)
//
#include <hip/hip_runtime.h>

using half8 = __attribute__((ext_vector_type(8))) _Float16;
using f32x4 = __attribute__((ext_vector_type(4))) float;

// ---------------------------------------------------------------------------
// Prep: fp32->fp16 conversions + layout transforms (one-time, parallel):
//  x16   : [75][112][76] fp16  (transposed from x[100][75][75], zero-padded)
//  wihI  : per layer [4H][Kv] fp16, row n = original gate row (n&3)*H + (n>>2)
//          -> GEMM output column n corresponds to (col = n>>2, gate = n&3).
//  whh16 : per layer [4H][H] fp16 (plain convert, original gate order)
//  biasI : summed b_ih+b_hh, interleaved to match wihI columns.
// ---------------------------------------------------------------------------
struct PrepPtrs {
    const float* wih[6];
    const float* whh[6];
    const float* bi[6];
    const float* bh[6];
    const float* x;
    _Float16* wihI[6];
    _Float16* whh16[6];
    float* biasI;
    _Float16* x16;
};

__global__ __launch_bounds__(256) void prep_kernel(PrepPtrs p) {
    int i = blockIdx.x * 256 + threadIdx.x;
    // x16: 8448 rows x 76
    if (i < 642048) {
        int row = i / 76, k = i - row * 76;
        int t = row / 112, b = row - t * 112;
        float v = (b < 100 && k < 75 && t < 75)
                      ? p.x[((size_t)b * 75 + t) * 75 + k]
                      : 0.0f;
        p.x16[i] = (_Float16)v;
        return;
    }
    i -= 642048;
    constexpr int HH[6] = {128, 128, 64, 64, 32, 32};
    constexpr int KK[6] = {75, 128, 128, 64, 64, 32};
    constexpr int KV[6] = {76, 128, 128, 64, 64, 32};
    #pragma unroll
    for (int lyr = 0; lyr < 6; ++lyr) {
        int cnt = 4 * HH[lyr] * KV[lyr];
        if (i < cnt) {
            int n = i / KV[lyr], k = i - n * KV[lyr];
            int col = n >> 2, G = n & 3;
            float v = (k < KK[lyr])
                          ? p.wih[lyr][(size_t)(G * HH[lyr] + col) * KK[lyr] + k]
                          : 0.0f;
            p.wihI[lyr][i] = (_Float16)v;
            return;
        }
        i -= cnt;
    }
    #pragma unroll
    for (int lyr = 0; lyr < 6; ++lyr) {
        int cnt = 4 * HH[lyr] * HH[lyr];
        if (i < cnt) {
            p.whh16[lyr][i] = (_Float16)p.whh[lyr][i];
            return;
        }
        i -= cnt;
    }
    constexpr int BOFF[6] = {0, 512, 1024, 1280, 1536, 1664};
    #pragma unroll
    for (int lyr = 0; lyr < 6; ++lyr) {
        int cnt = 4 * HH[lyr];
        if (i < cnt) {
            int col = i >> 2, G = i & 3;
            int src = G * HH[lyr] + col;
            p.biasI[BOFF[lyr] + i] = p.bi[lyr][src] + p.bh[lyr][src];
            return;
        }
        i -= cnt;
    }
}

// ---------------------------------------------------------------------------
// xg GEMM: computes xg[t][n][b] = sum_k A[t*112+b][k] * W[n][k] + bias[n]
// Output layout is TRANSPOSED per timestep: [75][4H][112] f32, so the
// recurrent kernel can load acc-layout fragments directly (dwordx4 over b).
// Grid: (150, N/64); bx>>1 = t, (bx&1)*48 = b-offset (tiles 0..63 / 48..111,
// overlap rows written twice with identical values).
// ---------------------------------------------------------------------------
template <int Ks>
__global__ __launch_bounds__(256) void gemm_xg(
    const _Float16* __restrict__ A, const _Float16* __restrict__ W,
    const float* __restrict__ bias, float* __restrict__ C, int Kv, int N) {
    constexpr int KP = Ks * 32;
    constexpr int LDK = KP + 8;
    __shared__ __align__(16) _Float16 Al[64][LDK];
    __shared__ __align__(16) _Float16 Wl[64][LDK];

    const int tid = threadIdx.x;
    const int tt = blockIdx.x >> 1;
    const int boff = (blockIdx.x & 1) * 48;
    const int n0 = blockIdx.y * 64;
    constexpr int HP = KP / 2;

    for (int idx = tid; idx < 64 * HP; idx += 256) {
        int row = idx / HP;
        int k = (idx - row * HP) * 2;
        unsigned int va = 0, vw = 0;
        if (k < Kv) {
            va = *(const unsigned int*)(A + (size_t)(tt * 112 + boff + row) * Kv + k);
            vw = *(const unsigned int*)(W + (size_t)(n0 + row) * Kv + k);
        }
        *(unsigned int*)&Al[row][k] = va;
        *(unsigned int*)&Wl[row][k] = vw;
    }
    __syncthreads();

    const int w = tid >> 6, l = tid & 63, hi = l >> 4;
    half8 a[Ks];
    #pragma unroll
    for (int kk = 0; kk < Ks; ++kk)
        a[kk] = *(const half8*)&Al[w * 16 + (l & 15)][kk * 32 + hi * 8];

    f32x4 acc[4];
    #pragma unroll
    for (int jt = 0; jt < 4; ++jt) {
        acc[jt] = f32x4{0.f, 0.f, 0.f, 0.f};
        #pragma unroll
        for (int kk = 0; kk < Ks; ++kk) {
            half8 b = *(const half8*)&Wl[jt * 16 + (l & 15)][kk * 32 + hi * 8];
            acc[jt] = __builtin_amdgcn_mfma_f32_16x16x32_f16(a[kk], b, acc[jt], 0, 0, 0);
        }
    }

    #pragma unroll
    for (int jt = 0; jt < 4; ++jt) {
        int n = n0 + jt * 16 + (l & 15);
        float bs = bias[n];
        #pragma unroll
        for (int r = 0; r < 4; ++r) {
            int b = boff + w * 16 + hi * 4 + r;  // 0..111
            C[((size_t)tt * N + n) * 112 + b] = acc[jt][r] + bs;
        }
    }
}

// ---------------------------------------------------------------------------
// Recurrent layer. 7 blocks x 16 batch rows; w_hh fragments in registers;
// h double-buffered in LDS. xg is in [t][4H][112] layout: each lane loads
// 4x dwordx4 that ARE the MFMA accumulator init (gates pre-summed with bias),
// 3 steps ahead of consumption. Raw s_barrier + lgkmcnt(0) only; global
// loads/stores stay in flight across barriers.
// ---------------------------------------------------------------------------
template <int H>
__global__ __launch_bounds__((H / 16) * 64) void lstm_rec(
    const float* __restrict__ xg,       // [75+3][4H][112] f32
    const _Float16* __restrict__ whh,   // [4H][H] fp16
    _Float16* __restrict__ hout) {      // [75][112][H] fp16
    constexpr int Ks = H / 32;
    constexpr int NW = H / 16;
    constexpr int LDH = H + 8;
    constexpr int XSTR = 4 * H * 112;   // floats per timestep in xg
    constexpr int HSTR = 112 * H;       // halfs per timestep in hout

    __shared__ __align__(16) _Float16 hbuf[2][16][LDH];

    const int tid = threadIdx.x;
    const int w = tid >> 6, l = tid & 63, hi = l >> 4;
    const int col = w * 16 + (l & 15);

    half8 bw[4][Ks];
    #pragma unroll
    for (int G = 0; G < 4; ++G)
        #pragma unroll
        for (int kk = 0; kk < Ks; ++kk)
            bw[G][kk] = *(const half8*)(whh + (size_t)(G * H + col) * H + kk * 32 + hi * 8);

    for (int i = tid; i < 2 * 16 * LDH; i += NW * 64) ((_Float16*)hbuf)[i] = (_Float16)0;
    __syncthreads();

    const float* xp = xg + (size_t)(col * 4) * 112 + blockIdx.x * 16 + hi * 4;
    _Float16* hop = hout + (size_t)(blockIdx.x * 16 + hi * 4) * H + col;

    f32x4 P0[4], P1[4], P2[4];
    #pragma unroll
    for (int G = 0; G < 4; ++G) P0[G] = *(const f32x4*)(xp + G * 112);
    xp += XSTR;
    #pragma unroll
    for (int G = 0; G < 4; ++G) P1[G] = *(const f32x4*)(xp + G * 112);
    xp += XSTR;
    #pragma unroll
    for (int G = 0; G < 4; ++G) P2[G] = *(const f32x4*)(xp + G * 112);
    xp += XSTR;

    float cst[4] = {0.f, 0.f, 0.f, 0.f};

#define LSTM_STEP(PA, CUR)                                                     \
    {                                                                          \
        f32x4 accI = PA[0], accF = PA[1], accG = PA[2], accO = PA[3];          \
        PA[0] = *(const f32x4*)(xp + 0 * 112);                                 \
        PA[1] = *(const f32x4*)(xp + 1 * 112);                                 \
        PA[2] = *(const f32x4*)(xp + 2 * 112);                                 \
        PA[3] = *(const f32x4*)(xp + 3 * 112);                                 \
        xp += XSTR;                                                            \
        half8 afr[Ks];                                                         \
        _Pragma("unroll") for (int kk = 0; kk < Ks; ++kk)                      \
            afr[kk] = *(const half8*)&hbuf[CUR][l & 15][kk * 32 + hi * 8];     \
        _Pragma("unroll") for (int kk = 0; kk < Ks; ++kk) {                    \
            accI = __builtin_amdgcn_mfma_f32_16x16x32_f16(afr[kk], bw[0][kk], accI, 0, 0, 0); \
            accF = __builtin_amdgcn_mfma_f32_16x16x32_f16(afr[kk], bw[1][kk], accF, 0, 0, 0); \
            accG = __builtin_amdgcn_mfma_f32_16x16x32_f16(afr[kk], bw[2][kk], accG, 0, 0, 0); \
            accO = __builtin_amdgcn_mfma_f32_16x16x32_f16(afr[kk], bw[3][kk], accO, 0, 0, 0); \
        }                                                                      \
        _Pragma("unroll") for (int r = 0; r < 4; ++r) {                        \
            float si = __builtin_amdgcn_rcpf(1.0f + __expf(-accI[r]));         \
            float sf = __builtin_amdgcn_rcpf(1.0f + __expf(-accF[r]));         \
            float so = __builtin_amdgcn_rcpf(1.0f + __expf(-accO[r]));         \
            float tg = 1.0f - 2.0f * __builtin_amdgcn_rcpf(1.0f + __expf(accG[r] + accG[r])); \
            float cn = sf * cst[r] + si * tg;                                  \
            cst[r] = cn;                                                       \
            float tc = 1.0f - 2.0f * __builtin_amdgcn_rcpf(1.0f + __expf(cn + cn)); \
            float hn = so * tc;                                                \
            _Float16 hv = (_Float16)hn;                                        \
            hbuf[CUR ^ 1][hi * 4 + r][col] = hv;                               \
            hop[r * H] = hv;                                                   \
        }                                                                      \
        hop += HSTR;                                                           \
        asm volatile("s_waitcnt lgkmcnt(0)" ::: "memory");                     \
        __builtin_amdgcn_s_barrier();                                          \
        asm volatile("" ::: "memory");                                         \
    }

    #pragma unroll 1
    for (int it = 0; it < 12; ++it) {
        LSTM_STEP(P0, 0) LSTM_STEP(P1, 1) LSTM_STEP(P2, 0)
        LSTM_STEP(P0, 1) LSTM_STEP(P1, 0) LSTM_STEP(P2, 1)
    }
    LSTM_STEP(P0, 0) LSTM_STEP(P1, 1) LSTM_STEP(P2, 0)
#undef LSTM_STEP
}

// ---------------------------------------------------------------------------
// Final linear: out[100][60] = h[.][2400] @ lin_w[60][2400]^T + lin_b,
// h stored as [75][112][32] fp16 (k = t*32 + hc). One wave per (b,o).
// ---------------------------------------------------------------------------
__global__ __launch_bounds__(256) void linear_out(
    const _Float16* __restrict__ h, const float* __restrict__ lw,
    const float* __restrict__ lb, float* __restrict__ out) {
    int wave = (blockIdx.x * 256 + threadIdx.x) >> 6;
    int l = threadIdx.x & 63;
    if (wave >= 6000) return;
    int b = wave / 60, o = wave - b * 60;
    int hc = l & 31, t0 = l >> 5;
    float acc = 0.f;
    for (int t = t0; t < 75; t += 2)
        acc += (float)h[((size_t)t * 112 + b) * 32 + hc] * lw[(size_t)o * 2400 + t * 32 + hc];
    #pragma unroll
    for (int s = 32; s; s >>= 1) acc += __shfl_xor(acc, s, 64);
    if (l == 0) out[b * 60 + o] = acc + lb[o];
}

// ---------------------------------------------------------------------------
extern "C" void kernel_launch(void* const* d_in, const int* in_sizes, int n_in,
                              void* d_out, int out_size, void* d_ws, size_t ws_size,
                              hipStream_t stream) {
    const float* x = (const float*)d_in[0];
    const float* wih[6];
    const float* whhp[6];
    const float* bih[6];
    const float* bhh[6];
    for (int i = 0; i < 6; ++i) {
        wih[i] = (const float*)d_in[1 + 4 * i];
        whhp[i] = (const float*)d_in[2 + 4 * i];
        bih[i] = (const float*)d_in[3 + 4 * i];
        bhh[i] = (const float*)d_in[4 + 4 * i];
    }
    const float* lw = (const float*)d_in[25];
    const float* lb = (const float*)d_in[26];
    float* out = (float*)d_out;

    char* ws = (char*)d_ws;
    size_t cur = 0;
    auto alloc = [&](size_t b) {
        size_t o = cur;
        cur += (b + 255) & ~(size_t)255;
        return o;
    };
    _Float16* x16 = (_Float16*)(ws + alloc((size_t)8448 * 76 * 2));
    _Float16* wI[6];
    const size_t wihBytes[6] = {77824, 131072, 65536, 32768, 16384, 8192};
    for (int i = 0; i < 6; ++i) wI[i] = (_Float16*)(ws + alloc(wihBytes[i]));
    _Float16* wH[6];
    const size_t whhBytes[6] = {131072, 131072, 32768, 32768, 8192, 8192};
    for (int i = 0; i < 6; ++i) wH[i] = (_Float16*)(ws + alloc(whhBytes[i]));
    float* biasI = (float*)(ws + alloc(1792 * 4));
    float* xg = (float*)(ws + alloc((size_t)78 * 512 * 112 * 4));  // +3t slack
    _Float16* hA = (_Float16*)(ws + alloc((size_t)8448 * 128 * 2));
    _Float16* hB = (_Float16*)(ws + alloc((size_t)8448 * 128 * 2));

    PrepPtrs pp;
    for (int i = 0; i < 6; ++i) {
        pp.wih[i] = wih[i];
        pp.whh[i] = whhp[i];
        pp.bi[i] = bih[i];
        pp.bh[i] = bhh[i];
        pp.wihI[i] = wI[i];
        pp.whh16[i] = wH[i];
    }
    pp.x = x;
    pp.biasI = biasI;
    pp.x16 = x16;
    prep_kernel<<<3835, 256, 0, stream>>>(pp);

    // layer 0: I=75 (Kv=76), H=128
    gemm_xg<3><<<dim3(150, 8), 256, 0, stream>>>(x16, wI[0], biasI + 0, xg, 76, 512);
    lstm_rec<128><<<7, 512, 0, stream>>>(xg, wH[0], hA);
    // layer 1: I=128, H=128
    gemm_xg<4><<<dim3(150, 8), 256, 0, stream>>>(hA, wI[1], biasI + 512, xg, 128, 512);
    lstm_rec<128><<<7, 512, 0, stream>>>(xg, wH[1], hB);
    // layer 2: I=128, H=64
    gemm_xg<4><<<dim3(150, 4), 256, 0, stream>>>(hB, wI[2], biasI + 1024, xg, 128, 256);
    lstm_rec<64><<<7, 256, 0, stream>>>(xg, wH[2], hA);
    // layer 3: I=64, H=64
    gemm_xg<2><<<dim3(150, 4), 256, 0, stream>>>(hA, wI[3], biasI + 1280, xg, 64, 256);
    lstm_rec<64><<<7, 256, 0, stream>>>(xg, wH[3], hB);
    // layer 4: I=64, H=32
    gemm_xg<2><<<dim3(150, 2), 256, 0, stream>>>(hB, wI[4], biasI + 1536, xg, 64, 128);
    lstm_rec<32><<<7, 128, 0, stream>>>(xg, wH[4], hA);
    // layer 5: I=32, H=32
    gemm_xg<1><<<dim3(150, 2), 256, 0, stream>>>(hA, wI[5], biasI + 1664, xg, 32, 128);
    lstm_rec<32><<<7, 128, 0, stream>>>(xg, wH[5], hB);

    linear_out<<<1500, 256, 0, stream>>>(hB, lw, lb, out);
}

// Round 4
// 391.982 us; speedup vs baseline: 1.1049x; 1.1049x over previous
//
#include <hip/hip_runtime.h>

using half8 = __attribute__((ext_vector_type(8))) _Float16;
using f32x4 = __attribute__((ext_vector_type(4))) float;

// ---------------------------------------------------------------------------
// Prep: fp32->fp16 conversions + layout transforms (one-time, parallel):
//  x16   : [75][112][76] fp16  (transposed from x[100][75][75], zero-padded)
//  wihI  : per layer [4H][Kv] fp16, row n = original gate row (n&3)*H + (n>>2)
//  whh16 : per layer [4H][H] fp16 (plain convert, original gate order)
//  biasI : summed b_ih+b_hh, interleaved to match wihI rows.
// ---------------------------------------------------------------------------
struct PrepPtrs {
    const float* wih[6];
    const float* whh[6];
    const float* bi[6];
    const float* bh[6];
    const float* x;
    _Float16* wihI[6];
    _Float16* whh16[6];
    float* biasI;
    _Float16* x16;
};

__global__ __launch_bounds__(256) void prep_kernel(PrepPtrs p) {
    int i = blockIdx.x * 256 + threadIdx.x;
    // x16: 8448 rows x 76
    if (i < 642048) {
        int row = i / 76, k = i - row * 76;
        int t = row / 112, b = row - t * 112;
        float v = (b < 100 && k < 75 && t < 75)
                      ? p.x[((size_t)b * 75 + t) * 75 + k]
                      : 0.0f;
        p.x16[i] = (_Float16)v;
        return;
    }
    i -= 642048;
    constexpr int HH[6] = {128, 128, 64, 64, 32, 32};
    constexpr int KK[6] = {75, 128, 128, 64, 64, 32};
    constexpr int KV[6] = {76, 128, 128, 64, 64, 32};
    #pragma unroll
    for (int lyr = 0; lyr < 6; ++lyr) {
        int cnt = 4 * HH[lyr] * KV[lyr];
        if (i < cnt) {
            int n = i / KV[lyr], k = i - n * KV[lyr];
            int col = n >> 2, G = n & 3;
            float v = (k < KK[lyr])
                          ? p.wih[lyr][(size_t)(G * HH[lyr] + col) * KK[lyr] + k]
                          : 0.0f;
            p.wihI[lyr][i] = (_Float16)v;
            return;
        }
        i -= cnt;
    }
    #pragma unroll
    for (int lyr = 0; lyr < 6; ++lyr) {
        int cnt = 4 * HH[lyr] * HH[lyr];
        if (i < cnt) {
            p.whh16[lyr][i] = (_Float16)p.whh[lyr][i];
            return;
        }
        i -= cnt;
    }
    constexpr int BOFF[6] = {0, 512, 1024, 1280, 1536, 1664};
    #pragma unroll
    for (int lyr = 0; lyr < 6; ++lyr) {
        int cnt = 4 * HH[lyr];
        if (i < cnt) {
            int col = i >> 2, G = i & 3;
            int src = G * HH[lyr] + col;
            p.biasI[BOFF[lyr] + i] = p.bi[lyr][src] + p.bh[lyr][src];
            return;
        }
        i -= cnt;
    }
}

// ---------------------------------------------------------------------------
// xg GEMM: xg[t][bx][n][bs] = sum_k A[t*112+bx*16+bs][k] * W[n][k] + bias[n]
// Output layout [75][7][4H][16] f32: per-recurrent-block CONTIGUOUS 32KB
// per timestep, and a lane's dwordx4 at (n, bs=hi*4) is exactly one MFMA
// accumulator fragment. Grid: (150, N/64); bx>>1 = t, (bx&1)*48 = b-offset
// (tiles 0..63 / 48..111; overlap written twice with identical values).
// ---------------------------------------------------------------------------
template <int Ks>
__global__ __launch_bounds__(256) void gemm_xg(
    const _Float16* __restrict__ A, const _Float16* __restrict__ W,
    const float* __restrict__ bias, float* __restrict__ C, int Kv, int N) {
    constexpr int KP = Ks * 32;
    constexpr int LDK = KP + 8;
    __shared__ __align__(16) _Float16 Al[64][LDK];
    __shared__ __align__(16) _Float16 Wl[64][LDK];

    const int tid = threadIdx.x;
    const int tt = blockIdx.x >> 1;
    const int boff = (blockIdx.x & 1) * 48;
    const int n0 = blockIdx.y * 64;
    constexpr int HP = KP / 2;

    for (int idx = tid; idx < 64 * HP; idx += 256) {
        int row = idx / HP;
        int k = (idx - row * HP) * 2;
        unsigned int va = 0, vw = 0;
        if (k < Kv) {
            va = *(const unsigned int*)(A + (size_t)(tt * 112 + boff + row) * Kv + k);
            vw = *(const unsigned int*)(W + (size_t)(n0 + row) * Kv + k);
        }
        *(unsigned int*)&Al[row][k] = va;
        *(unsigned int*)&Wl[row][k] = vw;
    }
    __syncthreads();

    const int w = tid >> 6, l = tid & 63, hi = l >> 4;
    half8 a[Ks];
    #pragma unroll
    for (int kk = 0; kk < Ks; ++kk)
        a[kk] = *(const half8*)&Al[w * 16 + (l & 15)][kk * 32 + hi * 8];

    f32x4 acc[4];
    #pragma unroll
    for (int jt = 0; jt < 4; ++jt) {
        acc[jt] = f32x4{0.f, 0.f, 0.f, 0.f};
        #pragma unroll
        for (int kk = 0; kk < Ks; ++kk) {
            half8 b = *(const half8*)&Wl[jt * 16 + (l & 15)][kk * 32 + hi * 8];
            acc[jt] = __builtin_amdgcn_mfma_f32_16x16x32_f16(a[kk], b, acc[jt], 0, 0, 0);
        }
    }

    const int bx7 = (boff >> 4) + w;  // batch tile 0..6
    #pragma unroll
    for (int jt = 0; jt < 4; ++jt) {
        int n = n0 + jt * 16 + (l & 15);
        float bs = bias[n];
        f32x4 v = acc[jt];
        v[0] += bs; v[1] += bs; v[2] += bs; v[3] += bs;
        *(f32x4*)(C + ((size_t)(tt * 7 + bx7) * N + n) * 16 + hi * 4) = v;
    }
}

// ---------------------------------------------------------------------------
// Recurrent layer. 7 blocks x 16 batch rows; w_hh fragments in registers;
// h double-buffered in LDS. xg in [t][7][4H][16]: each block streams one
// contiguous 32KB chunk per step; each lane's 4 dwordx4 ARE the MFMA
// accumulator init, prefetched 3 steps ahead. Clobber-free barrier keeps
// global loads/stores in flight across steps (counted vmcnt at use).
// ---------------------------------------------------------------------------
template <int H>
__global__ __launch_bounds__((H / 16) * 64) void lstm_rec(
    const float* __restrict__ xg,       // [75+3][7][4H][16] f32
    const _Float16* __restrict__ whh,   // [4H][H] fp16
    _Float16* __restrict__ hout) {      // [75][112][H] fp16
    constexpr int Ks = H / 32;
    constexpr int NW = H / 16;
    constexpr int LDH = H + 8;
    constexpr int XSTR = 448 * H;       // floats per timestep in xg (7*4H*16)
    constexpr int HSTR = 112 * H;       // halfs per timestep in hout

    __shared__ __align__(16) _Float16 hbuf[2][16][LDH];

    const int tid = threadIdx.x;
    const int w = tid >> 6, l = tid & 63, hi = l >> 4;
    const int col = w * 16 + (l & 15);

    half8 bw[4][Ks];
    #pragma unroll
    for (int G = 0; G < 4; ++G)
        #pragma unroll
        for (int kk = 0; kk < Ks; ++kk)
            bw[G][kk] = *(const half8*)(whh + (size_t)(G * H + col) * H + kk * 32 + hi * 8);

    for (int i = tid; i < 2 * 16 * LDH; i += NW * 64) ((_Float16*)hbuf)[i] = (_Float16)0;
    __syncthreads();

    const float* xp = xg + ((size_t)blockIdx.x * 4 * H + col * 4) * 16 + hi * 4;
    _Float16* hop = hout + (size_t)(blockIdx.x * 16 + hi * 4) * H + col;

    f32x4 P0[4], P1[4], P2[4];
    #pragma unroll
    for (int G = 0; G < 4; ++G) P0[G] = *(const f32x4*)(xp + G * 16);
    xp += XSTR;
    #pragma unroll
    for (int G = 0; G < 4; ++G) P1[G] = *(const f32x4*)(xp + G * 16);
    xp += XSTR;
    #pragma unroll
    for (int G = 0; G < 4; ++G) P2[G] = *(const f32x4*)(xp + G * 16);
    xp += XSTR;

    float cst[4] = {0.f, 0.f, 0.f, 0.f};

#define LSTM_STEP(PA, CUR)                                                     \
    {                                                                          \
        f32x4 accI = PA[0], accF = PA[1], accG = PA[2], accO = PA[3];          \
        PA[0] = *(const f32x4*)(xp + 0 * 16);                                  \
        PA[1] = *(const f32x4*)(xp + 1 * 16);                                  \
        PA[2] = *(const f32x4*)(xp + 2 * 16);                                  \
        PA[3] = *(const f32x4*)(xp + 3 * 16);                                  \
        xp += XSTR;                                                            \
        half8 afr[Ks];                                                         \
        _Pragma("unroll") for (int kk = 0; kk < Ks; ++kk)                      \
            afr[kk] = *(const half8*)&hbuf[CUR][l & 15][kk * 32 + hi * 8];     \
        _Pragma("unroll") for (int kk = 0; kk < Ks; ++kk) {                    \
            accI = __builtin_amdgcn_mfma_f32_16x16x32_f16(afr[kk], bw[0][kk], accI, 0, 0, 0); \
            accF = __builtin_amdgcn_mfma_f32_16x16x32_f16(afr[kk], bw[1][kk], accF, 0, 0, 0); \
            accG = __builtin_amdgcn_mfma_f32_16x16x32_f16(afr[kk], bw[2][kk], accG, 0, 0, 0); \
            accO = __builtin_amdgcn_mfma_f32_16x16x32_f16(afr[kk], bw[3][kk], accO, 0, 0, 0); \
        }                                                                      \
        _Pragma("unroll") for (int r = 0; r < 4; ++r) {                        \
            float si = __builtin_amdgcn_rcpf(1.0f + __expf(-accI[r]));         \
            float sf = __builtin_amdgcn_rcpf(1.0f + __expf(-accF[r]));         \
            float so = __builtin_amdgcn_rcpf(1.0f + __expf(-accO[r]));         \
            float tg = 1.0f - 2.0f * __builtin_amdgcn_rcpf(1.0f + __expf(accG[r] + accG[r])); \
            float cn = sf * cst[r] + si * tg;                                  \
            cst[r] = cn;                                                       \
            float tc = 1.0f - 2.0f * __builtin_amdgcn_rcpf(1.0f + __expf(cn + cn)); \
            float hn = so * tc;                                                \
            _Float16 hv = (_Float16)hn;                                        \
            hbuf[CUR ^ 1][hi * 4 + r][col] = hv;                               \
            hop[r * H] = hv;                                                   \
        }                                                                      \
        hop += HSTR;                                                           \
        __builtin_amdgcn_sched_barrier(0);                                     \
        asm volatile("s_waitcnt lgkmcnt(0)");                                  \
        __builtin_amdgcn_sched_barrier(0);                                     \
        __builtin_amdgcn_s_barrier();                                          \
        __builtin_amdgcn_sched_barrier(0);                                     \
    }

    #pragma unroll 1
    for (int it = 0; it < 12; ++it) {
        LSTM_STEP(P0, 0) LSTM_STEP(P1, 1) LSTM_STEP(P2, 0)
        LSTM_STEP(P0, 1) LSTM_STEP(P1, 0) LSTM_STEP(P2, 1)
    }
    LSTM_STEP(P0, 0) LSTM_STEP(P1, 1) LSTM_STEP(P2, 0)
#undef LSTM_STEP
}

// ---------------------------------------------------------------------------
// Final linear: out[100][60] = h[.][2400] @ lin_w[60][2400]^T + lin_b,
// h stored as [75][112][32] fp16 (k = t*32 + hc). One wave per (b,o).
// ---------------------------------------------------------------------------
__global__ __launch_bounds__(256) void linear_out(
    const _Float16* __restrict__ h, const float* __restrict__ lw,
    const float* __restrict__ lb, float* __restrict__ out) {
    int wave = (blockIdx.x * 256 + threadIdx.x) >> 6;
    int l = threadIdx.x & 63;
    if (wave >= 6000) return;
    int b = wave / 60, o = wave - b * 60;
    int hc = l & 31, t0 = l >> 5;
    float acc = 0.f;
    for (int t = t0; t < 75; t += 2)
        acc += (float)h[((size_t)t * 112 + b) * 32 + hc] * lw[(size_t)o * 2400 + t * 32 + hc];
    #pragma unroll
    for (int s = 32; s; s >>= 1) acc += __shfl_xor(acc, s, 64);
    if (l == 0) out[b * 60 + o] = acc + lb[o];
}

// ---------------------------------------------------------------------------
extern "C" void kernel_launch(void* const* d_in, const int* in_sizes, int n_in,
                              void* d_out, int out_size, void* d_ws, size_t ws_size,
                              hipStream_t stream) {
    const float* x = (const float*)d_in[0];
    const float* wih[6];
    const float* whhp[6];
    const float* bih[6];
    const float* bhh[6];
    for (int i = 0; i < 6; ++i) {
        wih[i] = (const float*)d_in[1 + 4 * i];
        whhp[i] = (const float*)d_in[2 + 4 * i];
        bih[i] = (const float*)d_in[3 + 4 * i];
        bhh[i] = (const float*)d_in[4 + 4 * i];
    }
    const float* lw = (const float*)d_in[25];
    const float* lb = (const float*)d_in[26];
    float* out = (float*)d_out;

    char* ws = (char*)d_ws;
    size_t cur = 0;
    auto alloc = [&](size_t b) {
        size_t o = cur;
        cur += (b + 255) & ~(size_t)255;
        return o;
    };
    _Float16* x16 = (_Float16*)(ws + alloc((size_t)8448 * 76 * 2));
    _Float16* wI[6];
    const size_t wihBytes[6] = {77824, 131072, 65536, 32768, 16384, 8192};
    for (int i = 0; i < 6; ++i) wI[i] = (_Float16*)(ws + alloc(wihBytes[i]));
    _Float16* wH[6];
    const size_t whhBytes[6] = {131072, 131072, 32768, 32768, 8192, 8192};
    for (int i = 0; i < 6; ++i) wH[i] = (_Float16*)(ws + alloc(whhBytes[i]));
    float* biasI = (float*)(ws + alloc(1792 * 4));
    float* xg = (float*)(ws + alloc((size_t)78 * 7 * 512 * 16 * 4));  // +3t slack
    _Float16* hA = (_Float16*)(ws + alloc((size_t)8448 * 128 * 2));
    _Float16* hB = (_Float16*)(ws + alloc((size_t)8448 * 128 * 2));

    PrepPtrs pp;
    for (int i = 0; i < 6; ++i) {
        pp.wih[i] = wih[i];
        pp.whh[i] = whhp[i];
        pp.bi[i] = bih[i];
        pp.bh[i] = bhh[i];
        pp.wihI[i] = wI[i];
        pp.whh16[i] = wH[i];
    }
    pp.x = x;
    pp.biasI = biasI;
    pp.x16 = x16;
    prep_kernel<<<3835, 256, 0, stream>>>(pp);

    // layer 0: I=75 (Kv=76), H=128
    gemm_xg<3><<<dim3(150, 8), 256, 0, stream>>>(x16, wI[0], biasI + 0, xg, 76, 512);
    lstm_rec<128><<<7, 512, 0, stream>>>(xg, wH[0], hA);
    // layer 1: I=128, H=128
    gemm_xg<4><<<dim3(150, 8), 256, 0, stream>>>(hA, wI[1], biasI + 512, xg, 128, 512);
    lstm_rec<128><<<7, 512, 0, stream>>>(xg, wH[1], hB);
    // layer 2: I=128, H=64
    gemm_xg<4><<<dim3(150, 4), 256, 0, stream>>>(hB, wI[2], biasI + 1024, xg, 128, 256);
    lstm_rec<64><<<7, 256, 0, stream>>>(xg, wH[2], hA);
    // layer 3: I=64, H=64
    gemm_xg<2><<<dim3(150, 4), 256, 0, stream>>>(hA, wI[3], biasI + 1280, xg, 64, 256);
    lstm_rec<64><<<7, 256, 0, stream>>>(xg, wH[3], hB);
    // layer 4: I=64, H=32
    gemm_xg<2><<<dim3(150, 2), 256, 0, stream>>>(hB, wI[4], biasI + 1536, xg, 64, 128);
    lstm_rec<32><<<7, 128, 0, stream>>>(xg, wH[4], hA);
    // layer 5: I=32, H=32
    gemm_xg<1><<<dim3(150, 2), 256, 0, stream>>>(hA, wI[5], biasI + 1664, xg, 32, 128);
    lstm_rec<32><<<7, 128, 0, stream>>>(xg, wH[5], hB);

    linear_out<<<1500, 256, 0, stream>>>(hB, lw, lb, out);
}

// Round 6
// 315.998 us; speedup vs baseline: 1.3706x; 1.2405x over previous
//
#include <hip/hip_runtime.h>

using half8 = __attribute__((ext_vector_type(8))) _Float16;
using f32x4 = __attribute__((ext_vector_type(4))) float;

__device__ __forceinline__ float sigmf(float x) {
    return __builtin_amdgcn_rcpf(1.0f + __expf(-x));
}
__device__ __forceinline__ float tanhx(float x) {
    return 1.0f - 2.0f * __builtin_amdgcn_rcpf(1.0f + __expf(x + x));
}

// ---------------------------------------------------------------------------
// Prep: fp32->fp16 conversions + layout transforms (one-time, parallel):
//  x16   : [75][112][76] fp16  (transposed from x[100][75][75], zero-padded)
//  wihI  : per layer [4H][Kv] fp16, row n = original gate row (n&3)*H + (n>>2)
//  whh16 : per layer [4H][H] fp16 (plain convert, original gate order)
//  biasI : summed b_ih+b_hh, interleaved to match wihI rows.
// ---------------------------------------------------------------------------
struct PrepPtrs {
    const float* wih[6];
    const float* whh[6];
    const float* bi[6];
    const float* bh[6];
    const float* x;
    _Float16* wihI[6];
    _Float16* whh16[6];
    float* biasI;
    _Float16* x16;
};

__global__ __launch_bounds__(256) void prep_kernel(PrepPtrs p) {
    int i = blockIdx.x * 256 + threadIdx.x;
    // x16: 8448 rows x 76
    if (i < 642048) {
        int row = i / 76, k = i - row * 76;
        int t = row / 112, b = row - t * 112;
        float v = (b < 100 && k < 75 && t < 75)
                      ? p.x[((size_t)b * 75 + t) * 75 + k]
                      : 0.0f;
        p.x16[i] = (_Float16)v;
        return;
    }
    i -= 642048;
    constexpr int HH[6] = {128, 128, 64, 64, 32, 32};
    constexpr int KK[6] = {75, 128, 128, 64, 64, 32};
    constexpr int KV[6] = {76, 128, 128, 64, 64, 32};
    #pragma unroll
    for (int lyr = 0; lyr < 6; ++lyr) {
        int cnt = 4 * HH[lyr] * KV[lyr];
        if (i < cnt) {
            int n = i / KV[lyr], k = i - n * KV[lyr];
            int col = n >> 2, G = n & 3;
            float v = (k < KK[lyr])
                          ? p.wih[lyr][(size_t)(G * HH[lyr] + col) * KK[lyr] + k]
                          : 0.0f;
            p.wihI[lyr][i] = (_Float16)v;
            return;
        }
        i -= cnt;
    }
    #pragma unroll
    for (int lyr = 0; lyr < 6; ++lyr) {
        int cnt = 4 * HH[lyr] * HH[lyr];
        if (i < cnt) {
            p.whh16[lyr][i] = (_Float16)p.whh[lyr][i];
            return;
        }
        i -= cnt;
    }
    constexpr int BOFF[6] = {0, 512, 1024, 1280, 1536, 1664};
    #pragma unroll
    for (int lyr = 0; lyr < 6; ++lyr) {
        int cnt = 4 * HH[lyr];
        if (i < cnt) {
            int col = i >> 2, G = i & 3;
            int src = G * HH[lyr] + col;
            p.biasI[BOFF[lyr] + i] = p.bi[lyr][src] + p.bh[lyr][src];
            return;
        }
        i -= cnt;
    }
}

// ---------------------------------------------------------------------------
// xg GEMM: xg[t][bx][n][bs] = sum_k A[t*112+bx*4+bs][k] * W[n][k] + bias[n]
// Output layout [75][28][4H][4] f32: per-recurrent-block (4 batch rows)
// contiguous 8KB (H=128) per timestep; a lane's f32x4 at (n, bs0..3) is one
// MFMA C fragment (rows = batch). Grid: (150, N/64); bx>>1 = t,
// (bx&1)*48 = batch offset (tiles 0..63 / 48..111, overlap written twice).
// ---------------------------------------------------------------------------
template <int Ks>
__global__ __launch_bounds__(256) void gemm_xg(
    const _Float16* __restrict__ A, const _Float16* __restrict__ W,
    const float* __restrict__ bias, float* __restrict__ C, int Kv, int N) {
    constexpr int KP = Ks * 32;
    constexpr int LDK = KP + 8;
    __shared__ __align__(16) _Float16 Al[64][LDK];
    __shared__ __align__(16) _Float16 Wl[64][LDK];

    const int tid = threadIdx.x;
    const int tt = blockIdx.x >> 1;
    const int boff = (blockIdx.x & 1) * 48;
    const int n0 = blockIdx.y * 64;
    constexpr int HP = KP / 2;

    for (int idx = tid; idx < 64 * HP; idx += 256) {
        int row = idx / HP;
        int k = (idx - row * HP) * 2;
        unsigned int va = 0, vw = 0;
        if (k < Kv) {
            va = *(const unsigned int*)(A + (size_t)(tt * 112 + boff + row) * Kv + k);
            vw = *(const unsigned int*)(W + (size_t)(n0 + row) * Kv + k);
        }
        *(unsigned int*)&Al[row][k] = va;
        *(unsigned int*)&Wl[row][k] = vw;
    }
    __syncthreads();

    const int w = tid >> 6, l = tid & 63, hi = l >> 4;
    half8 a[Ks];
    #pragma unroll
    for (int kk = 0; kk < Ks; ++kk)
        a[kk] = *(const half8*)&Al[w * 16 + (l & 15)][kk * 32 + hi * 8];

    f32x4 acc[4];
    #pragma unroll
    for (int jt = 0; jt < 4; ++jt) {
        acc[jt] = f32x4{0.f, 0.f, 0.f, 0.f};
        #pragma unroll
        for (int kk = 0; kk < Ks; ++kk) {
            half8 b = *(const half8*)&Wl[jt * 16 + (l & 15)][kk * 32 + hi * 8];
            acc[jt] = __builtin_amdgcn_mfma_f32_16x16x32_f16(a[kk], b, acc[jt], 0, 0, 0);
        }
    }

    const int bx = (boff >> 2) + w * 4 + hi;  // 4-row batch block 0..27
    #pragma unroll
    for (int jt = 0; jt < 4; ++jt) {
        int n = n0 + jt * 16 + (l & 15);
        float bs = bias[n];
        f32x4 v = acc[jt];
        v[0] += bs; v[1] += bs; v[2] += bs; v[3] += bs;
        *(f32x4*)(C + ((size_t)(tt * 28 + bx) * N + n) * 4) = v;
    }
}

// ---------------------------------------------------------------------------
// Recurrent layer: 25 blocks x 4 batch rows (more CUs on the fixed VALU work).
// Phase A: w_hh-in-registers MFMA, xg rides in as C-init (register P, plain
// HIP loads, 3 steps deep); valid C rows (hi==0 lanes) written to an LDS gate
// buffer. Phase B: after barrier, EVERY lane activates exactly ONE h-element
// (4x less transcendental work per lane than the fragment-bound layout),
// writes h to hbuf (fp16) + global. Clobber-free barrier tails (round-4
// proven) keep global loads/stores in flight across steps.
// ---------------------------------------------------------------------------
template <int H>
__global__ __launch_bounds__(4 * H) void lstm_rec(
    const float* __restrict__ xg,       // [75+3][28][4H][4] f32
    const _Float16* __restrict__ whh,   // [4H][H] fp16
    _Float16* __restrict__ hout) {      // [75][112][H] fp16
    constexpr int Ks = H / 32;
    constexpr int LDH = H + 8;
    constexpr int XSTR = 448 * H;       // floats per timestep (28*4H*4)
    constexpr int HSTR = 112 * H;       // halfs per timestep in hout

    __shared__ __align__(16) _Float16 hbuf[2][16][LDH];
    __shared__ __align__(16) float gbuf[4][H][4];  // [b][col][i,f,g,o]

    const int tid = threadIdx.x;
    const int w = tid >> 6, l = tid & 63, hi = l >> 4;
    const int col = w * 16 + (l & 15);
    const int blk = blockIdx.x;         // 0..24, batch rows blk*4..blk*4+3
    const int rb = tid / H;             // phase-B batch row 0..3
    const int rc = tid & (H - 1);       // phase-B hidden col

    half8 bw[4][Ks];
    #pragma unroll
    for (int G = 0; G < 4; ++G)
        #pragma unroll
        for (int kk = 0; kk < Ks; ++kk)
            bw[G][kk] = *(const half8*)(whh + (size_t)(G * H + col) * H + kk * 32 + hi * 8);

    for (int i = tid; i < 2 * 16 * LDH; i += 4 * H) ((_Float16*)hbuf)[i] = (_Float16)0;
    __syncthreads();

    const float* xp = xg + (size_t)blk * (4 * H * 4) + col * 16;
    _Float16* hop = hout + (size_t)(blk * 4 + rb) * H + rc;

    f32x4 P0[4], P1[4], P2[4];
#define XLOAD(PA)                                                             \
    PA[0] = *(const f32x4*)(xp + 0);                                          \
    PA[1] = *(const f32x4*)(xp + 4);                                          \
    PA[2] = *(const f32x4*)(xp + 8);                                          \
    PA[3] = *(const f32x4*)(xp + 12);                                         \
    xp += XSTR;

    XLOAD(P0)
    XLOAD(P1)
    XLOAD(P2)

    float cst = 0.f;

#define TAIL                                                                  \
    __builtin_amdgcn_sched_barrier(0);                                        \
    asm volatile("s_waitcnt lgkmcnt(0)");                                     \
    __builtin_amdgcn_sched_barrier(0);                                        \
    __builtin_amdgcn_s_barrier();                                             \
    __builtin_amdgcn_sched_barrier(0);

#define LSTM_STEP(PA, CUR)                                                    \
    {                                                                         \
        half8 afr[Ks];                                                        \
        _Pragma("unroll") for (int kk = 0; kk < Ks; ++kk)                     \
            afr[kk] = *(const half8*)&hbuf[CUR][l & 15][kk * 32 + hi * 8];    \
        f32x4 accI = PA[0], accF = PA[1], accG4 = PA[2], accO = PA[3];        \
        XLOAD(PA)                                                             \
        _Pragma("unroll") for (int kk = 0; kk < Ks; ++kk) {                   \
            accI = __builtin_amdgcn_mfma_f32_16x16x32_f16(afr[kk], bw[0][kk], accI, 0, 0, 0);  \
            accF = __builtin_amdgcn_mfma_f32_16x16x32_f16(afr[kk], bw[1][kk], accF, 0, 0, 0);  \
            accG4 = __builtin_amdgcn_mfma_f32_16x16x32_f16(afr[kk], bw[2][kk], accG4, 0, 0, 0);\
            accO = __builtin_amdgcn_mfma_f32_16x16x32_f16(afr[kk], bw[3][kk], accO, 0, 0, 0);  \
        }                                                                     \
        if (hi == 0) {                                                        \
            *(f32x4*)&gbuf[0][col][0] = f32x4{accI[0], accF[0], accG4[0], accO[0]}; \
            *(f32x4*)&gbuf[1][col][0] = f32x4{accI[1], accF[1], accG4[1], accO[1]}; \
            *(f32x4*)&gbuf[2][col][0] = f32x4{accI[2], accF[2], accG4[2], accO[2]}; \
            *(f32x4*)&gbuf[3][col][0] = f32x4{accI[3], accF[3], accG4[3], accO[3]}; \
        }                                                                     \
        TAIL                                                                  \
        f32x4 g = *(const f32x4*)&gbuf[rb][rc][0];                            \
        float si = sigmf(g[0]);                                               \
        float sf = sigmf(g[1]);                                               \
        float tg = tanhx(g[2]);                                               \
        float so = sigmf(g[3]);                                               \
        float cn = sf * cst + si * tg;                                        \
        cst = cn;                                                             \
        float hn = so * tanhx(cn);                                            \
        _Float16 hv = (_Float16)hn;                                           \
        hbuf[CUR ^ 1][rb][rc] = hv;                                           \
        *hop = hv;                                                            \
        hop += HSTR;                                                          \
        TAIL                                                                  \
    }

    #pragma unroll 1
    for (int it = 0; it < 12; ++it) {
        LSTM_STEP(P0, 0) LSTM_STEP(P1, 1) LSTM_STEP(P2, 0)
        LSTM_STEP(P0, 1) LSTM_STEP(P1, 0) LSTM_STEP(P2, 1)
    }
    LSTM_STEP(P0, 0) LSTM_STEP(P1, 1) LSTM_STEP(P2, 0)
#undef LSTM_STEP
#undef XLOAD
#undef TAIL
}

// ---------------------------------------------------------------------------
// Final linear: out[100][60] = h[.][2400] @ lin_w[60][2400]^T + lin_b,
// h stored as [75][112][32] fp16 (k = t*32 + hc). One wave per (b,o).
// ---------------------------------------------------------------------------
__global__ __launch_bounds__(256) void linear_out(
    const _Float16* __restrict__ h, const float* __restrict__ lw,
    const float* __restrict__ lb, float* __restrict__ out) {
    int wave = (blockIdx.x * 256 + threadIdx.x) >> 6;
    int l = threadIdx.x & 63;
    if (wave >= 6000) return;
    int b = wave / 60, o = wave - b * 60;
    int hc = l & 31, t0 = l >> 5;
    float acc = 0.f;
    for (int t = t0; t < 75; t += 2)
        acc += (float)h[((size_t)t * 112 + b) * 32 + hc] * lw[(size_t)o * 2400 + t * 32 + hc];
    #pragma unroll
    for (int s = 32; s; s >>= 1) acc += __shfl_xor(acc, s, 64);
    if (l == 0) out[b * 60 + o] = acc + lb[o];
}

// ---------------------------------------------------------------------------
extern "C" void kernel_launch(void* const* d_in, const int* in_sizes, int n_in,
                              void* d_out, int out_size, void* d_ws, size_t ws_size,
                              hipStream_t stream) {
    const float* x = (const float*)d_in[0];
    const float* wih[6];
    const float* whhp[6];
    const float* bih[6];
    const float* bhh[6];
    for (int i = 0; i < 6; ++i) {
        wih[i] = (const float*)d_in[1 + 4 * i];
        whhp[i] = (const float*)d_in[2 + 4 * i];
        bih[i] = (const float*)d_in[3 + 4 * i];
        bhh[i] = (const float*)d_in[4 + 4 * i];
    }
    const float* lw = (const float*)d_in[25];
    const float* lb = (const float*)d_in[26];
    float* out = (float*)d_out;

    char* ws = (char*)d_ws;
    size_t cur = 0;
    auto alloc = [&](size_t b) {
        size_t o = cur;
        cur += (b + 255) & ~(size_t)255;
        return o;
    };
    _Float16* x16 = (_Float16*)(ws + alloc((size_t)8448 * 76 * 2));
    _Float16* wI[6];
    const size_t wihBytes[6] = {77824, 131072, 65536, 32768, 16384, 8192};
    for (int i = 0; i < 6; ++i) wI[i] = (_Float16*)(ws + alloc(wihBytes[i]));
    _Float16* wH[6];
    const size_t whhBytes[6] = {131072, 131072, 32768, 32768, 8192, 8192};
    for (int i = 0; i < 6; ++i) wH[i] = (_Float16*)(ws + alloc(whhBytes[i]));
    float* biasI = (float*)(ws + alloc(1792 * 4));
    float* xg = (float*)(ws + alloc((size_t)78 * 28 * 512 * 4 * 4));  // +3t slack
    _Float16* hA = (_Float16*)(ws + alloc((size_t)8448 * 128 * 2));
    _Float16* hB = (_Float16*)(ws + alloc((size_t)8448 * 128 * 2));

    PrepPtrs pp;
    for (int i = 0; i < 6; ++i) {
        pp.wih[i] = wih[i];
        pp.whh[i] = whhp[i];
        pp.bi[i] = bih[i];
        pp.bh[i] = bhh[i];
        pp.wihI[i] = wI[i];
        pp.whh16[i] = wH[i];
    }
    pp.x = x;
    pp.biasI = biasI;
    pp.x16 = x16;
    prep_kernel<<<3835, 256, 0, stream>>>(pp);

    // layer 0: I=75 (Kv=76), H=128
    gemm_xg<3><<<dim3(150, 8), 256, 0, stream>>>(x16, wI[0], biasI + 0, xg, 76, 512);
    lstm_rec<128><<<25, 512, 0, stream>>>(xg, wH[0], hA);
    // layer 1: I=128, H=128
    gemm_xg<4><<<dim3(150, 8), 256, 0, stream>>>(hA, wI[1], biasI + 512, xg, 128, 512);
    lstm_rec<128><<<25, 512, 0, stream>>>(xg, wH[1], hB);
    // layer 2: I=128, H=64
    gemm_xg<4><<<dim3(150, 4), 256, 0, stream>>>(hB, wI[2], biasI + 1024, xg, 128, 256);
    lstm_rec<64><<<25, 256, 0, stream>>>(xg, wH[2], hA);
    // layer 3: I=64, H=64
    gemm_xg<2><<<dim3(150, 4), 256, 0, stream>>>(hA, wI[3], biasI + 1280, xg, 64, 256);
    lstm_rec<64><<<25, 256, 0, stream>>>(xg, wH[3], hB);
    // layer 4: I=64, H=32
    gemm_xg<2><<<dim3(150, 2), 256, 0, stream>>>(hB, wI[4], biasI + 1536, xg, 64, 128);
    lstm_rec<32><<<25, 128, 0, stream>>>(xg, wH[4], hA);
    // layer 5: I=32, H=32
    gemm_xg<1><<<dim3(150, 2), 256, 0, stream>>>(hA, wI[5], biasI + 1664, xg, 32, 128);
    lstm_rec<32><<<25, 128, 0, stream>>>(xg, wH[5], hB);

    linear_out<<<1500, 256, 0, stream>>>(hB, lw, lb, out);
}

// Round 7
// 244.573 us; speedup vs baseline: 1.7708x; 1.2920x over previous
//
#include <hip/hip_runtime.h>

using half8 = __attribute__((ext_vector_type(8))) _Float16;
using f32x4 = __attribute__((ext_vector_type(4))) float;

__device__ __forceinline__ float sigmf(float x) {
    return __builtin_amdgcn_rcpf(1.0f + __expf(-x));
}
__device__ __forceinline__ float tanhx(float x) {
    return 1.0f - 2.0f * __builtin_amdgcn_rcpf(1.0f + __expf(x + x));
}

// ---------------------------------------------------------------------------
// Prep: fp32->fp16 conversions + layout transforms (one-time, parallel):
//  x16   : [75][112][76] fp16  (transposed from x[100][75][75], zero-padded)
//  wihI  : per layer [4H][Kv] fp16, row n = original gate row (n&3)*H + (n>>2)
//  whh16 : per layer [4H][H] fp16 (plain convert, original gate order)
//  biasI : summed b_ih+b_hh, interleaved to match wihI rows.
// ---------------------------------------------------------------------------
struct PrepPtrs {
    const float* wih[6];
    const float* whh[6];
    const float* bi[6];
    const float* bh[6];
    const float* x;
    _Float16* wihI[6];
    _Float16* whh16[6];
    float* biasI;
    _Float16* x16;
};

__global__ __launch_bounds__(256) void prep_kernel(PrepPtrs p) {
    int i = blockIdx.x * 256 + threadIdx.x;
    // x16: 8448 rows x 76
    if (i < 642048) {
        int row = i / 76, k = i - row * 76;
        int t = row / 112, b = row - t * 112;
        float v = (b < 100 && k < 75 && t < 75)
                      ? p.x[((size_t)b * 75 + t) * 75 + k]
                      : 0.0f;
        p.x16[i] = (_Float16)v;
        return;
    }
    i -= 642048;
    constexpr int HH[6] = {128, 128, 64, 64, 32, 32};
    constexpr int KK[6] = {75, 128, 128, 64, 64, 32};
    constexpr int KV[6] = {76, 128, 128, 64, 64, 32};
    #pragma unroll
    for (int lyr = 0; lyr < 6; ++lyr) {
        int cnt = 4 * HH[lyr] * KV[lyr];
        if (i < cnt) {
            int n = i / KV[lyr], k = i - n * KV[lyr];
            int col = n >> 2, G = n & 3;
            float v = (k < KK[lyr])
                          ? p.wih[lyr][(size_t)(G * HH[lyr] + col) * KK[lyr] + k]
                          : 0.0f;
            p.wihI[lyr][i] = (_Float16)v;
            return;
        }
        i -= cnt;
    }
    #pragma unroll
    for (int lyr = 0; lyr < 6; ++lyr) {
        int cnt = 4 * HH[lyr] * HH[lyr];
        if (i < cnt) {
            p.whh16[lyr][i] = (_Float16)p.whh[lyr][i];
            return;
        }
        i -= cnt;
    }
    constexpr int BOFF[6] = {0, 512, 1024, 1280, 1536, 1664};
    #pragma unroll
    for (int lyr = 0; lyr < 6; ++lyr) {
        int cnt = 4 * HH[lyr];
        if (i < cnt) {
            int col = i >> 2, G = i & 3;
            int src = G * HH[lyr] + col;
            p.biasI[BOFF[lyr] + i] = p.bi[lyr][src] + p.bh[lyr][src];
            return;
        }
        i -= cnt;
    }
}

// ---------------------------------------------------------------------------
// xg GEMM: xg[t][bx][n][bs] = sum_k A[t*112+bx*4+bs][k] * W[n][k] + bias[n]
// Output layout [75][28][4H][4] f32: per-recurrent-block (4 batch rows)
// contiguous 8KB (H=128) per timestep; a lane's f32x4 at (n, bs0..3) is one
// MFMA C fragment (rows = batch). Grid: (150, N/64); bx>>1 = t,
// (bx&1)*48 = batch offset (tiles 0..63 / 48..111, overlap written twice).
// ---------------------------------------------------------------------------
template <int Ks>
__global__ __launch_bounds__(256) void gemm_xg(
    const _Float16* __restrict__ A, const _Float16* __restrict__ W,
    const float* __restrict__ bias, float* __restrict__ C, int Kv, int N) {
    constexpr int KP = Ks * 32;
    constexpr int LDK = KP + 8;
    __shared__ __align__(16) _Float16 Al[64][LDK];
    __shared__ __align__(16) _Float16 Wl[64][LDK];

    const int tid = threadIdx.x;
    const int tt = blockIdx.x >> 1;
    const int boff = (blockIdx.x & 1) * 48;
    const int n0 = blockIdx.y * 64;
    constexpr int HP = KP / 2;

    for (int idx = tid; idx < 64 * HP; idx += 256) {
        int row = idx / HP;
        int k = (idx - row * HP) * 2;
        unsigned int va = 0, vw = 0;
        if (k < Kv) {
            va = *(const unsigned int*)(A + (size_t)(tt * 112 + boff + row) * Kv + k);
            vw = *(const unsigned int*)(W + (size_t)(n0 + row) * Kv + k);
        }
        *(unsigned int*)&Al[row][k] = va;
        *(unsigned int*)&Wl[row][k] = vw;
    }
    __syncthreads();

    const int w = tid >> 6, l = tid & 63, hi = l >> 4;
    half8 a[Ks];
    #pragma unroll
    for (int kk = 0; kk < Ks; ++kk)
        a[kk] = *(const half8*)&Al[w * 16 + (l & 15)][kk * 32 + hi * 8];

    f32x4 acc[4];
    #pragma unroll
    for (int jt = 0; jt < 4; ++jt) {
        acc[jt] = f32x4{0.f, 0.f, 0.f, 0.f};
        #pragma unroll
        for (int kk = 0; kk < Ks; ++kk) {
            half8 b = *(const half8*)&Wl[jt * 16 + (l & 15)][kk * 32 + hi * 8];
            acc[jt] = __builtin_amdgcn_mfma_f32_16x16x32_f16(a[kk], b, acc[jt], 0, 0, 0);
        }
    }

    const int bx = (boff >> 2) + w * 4 + hi;  // 4-row batch block 0..27
    #pragma unroll
    for (int jt = 0; jt < 4; ++jt) {
        int n = n0 + jt * 16 + (l & 15);
        float bs = bias[n];
        f32x4 v = acc[jt];
        v[0] += bs; v[1] += bs; v[2] += bs; v[3] += bs;
        *(f32x4*)(C + ((size_t)(tt * 28 + bx) * N + n) * 4) = v;
    }
}

// ---------------------------------------------------------------------------
// Recurrent layer: 25 blocks x 4 batch rows, ONE barrier per step.
// Trick: A-fragment rows replicate the 4 real batch rows across the MFMA
// M-dim (read hbuf[(l&15)&3]) -> C row m = gate(batch m&3), so EVERY lane's
// acc[r] = gate(batch r, its col). No LDS gate redistribution needed: each
// lane selects batch=hi via static-index cndmask chains and activates exactly
// one h element. xg rides in as MFMA C-init (register P, 3 steps deep).
// ---------------------------------------------------------------------------
template <int H>
__global__ __launch_bounds__(4 * H) void lstm_rec(
    const float* __restrict__ xg,       // [75+3][28][4H][4] f32
    const _Float16* __restrict__ whh,   // [4H][H] fp16
    _Float16* __restrict__ hout) {      // [75][112][H] fp16
    constexpr int Ks = H / 32;
    constexpr int LDH = H + 8;
    constexpr int XSTR = 448 * H;       // floats per timestep (28*4H*4)
    constexpr int HSTR = 112 * H;       // halfs per timestep in hout

    __shared__ __align__(16) _Float16 hbuf[2][4][LDH];

    const int tid = threadIdx.x;
    const int w = tid >> 6, l = tid & 63, hi = l >> 4;
    const int col = w * 16 + (l & 15);
    const int blk = blockIdx.x;         // 0..24, batch rows blk*4..blk*4+3

    half8 bw[4][Ks];
    #pragma unroll
    for (int G = 0; G < 4; ++G)
        #pragma unroll
        for (int kk = 0; kk < Ks; ++kk)
            bw[G][kk] = *(const half8*)(whh + (size_t)(G * H + col) * H + kk * 32 + hi * 8);

    for (int i = tid; i < 2 * 4 * LDH; i += 4 * H) ((_Float16*)hbuf)[i] = (_Float16)0;
    __syncthreads();

    const float* xp = xg + (size_t)blk * (4 * H * 4) + col * 16;
    _Float16* hop = hout + (size_t)(blk * 4 + hi) * H + col;

    f32x4 P0[4], P1[4], P2[4];
#define XLOAD(PA)                                                             \
    PA[0] = *(const f32x4*)(xp + 0);                                          \
    PA[1] = *(const f32x4*)(xp + 4);                                          \
    PA[2] = *(const f32x4*)(xp + 8);                                          \
    PA[3] = *(const f32x4*)(xp + 12);                                         \
    xp += XSTR;

    XLOAD(P0)
    XLOAD(P1)
    XLOAD(P2)

    float cst = 0.f;

#define PICK(A4) ((hi & 2) ? ((hi & 1) ? A4[3] : A4[2]) : ((hi & 1) ? A4[1] : A4[0]))

#define LSTM_STEP(PA, CUR)                                                    \
    {                                                                         \
        half8 afr[Ks];                                                        \
        _Pragma("unroll") for (int kk = 0; kk < Ks; ++kk)                     \
            afr[kk] = *(const half8*)&hbuf[CUR][(l & 15) & 3][kk * 32 + hi * 8]; \
        f32x4 accI = PA[0], accF = PA[1], accG4 = PA[2], accO = PA[3];        \
        XLOAD(PA)                                                             \
        _Pragma("unroll") for (int kk = 0; kk < Ks; ++kk) {                   \
            accI = __builtin_amdgcn_mfma_f32_16x16x32_f16(afr[kk], bw[0][kk], accI, 0, 0, 0);  \
            accF = __builtin_amdgcn_mfma_f32_16x16x32_f16(afr[kk], bw[1][kk], accF, 0, 0, 0);  \
            accG4 = __builtin_amdgcn_mfma_f32_16x16x32_f16(afr[kk], bw[2][kk], accG4, 0, 0, 0);\
            accO = __builtin_amdgcn_mfma_f32_16x16x32_f16(afr[kk], bw[3][kk], accO, 0, 0, 0);  \
        }                                                                     \
        float gI = PICK(accI), gF = PICK(accF), gG = PICK(accG4), gO = PICK(accO); \
        float si = sigmf(gI);                                                 \
        float sf = sigmf(gF);                                                 \
        float tg = tanhx(gG);                                                 \
        float so = sigmf(gO);                                                 \
        float cn = sf * cst + si * tg;                                        \
        cst = cn;                                                             \
        float hn = so * tanhx(cn);                                            \
        _Float16 hv = (_Float16)hn;                                           \
        hbuf[CUR ^ 1][hi][col] = hv;                                          \
        *hop = hv;                                                            \
        hop += HSTR;                                                          \
        __builtin_amdgcn_sched_barrier(0);                                    \
        asm volatile("s_waitcnt lgkmcnt(0)");                                 \
        __builtin_amdgcn_sched_barrier(0);                                    \
        __builtin_amdgcn_s_barrier();                                         \
        __builtin_amdgcn_sched_barrier(0);                                    \
    }

    #pragma unroll 1
    for (int it = 0; it < 12; ++it) {
        LSTM_STEP(P0, 0) LSTM_STEP(P1, 1) LSTM_STEP(P2, 0)
        LSTM_STEP(P0, 1) LSTM_STEP(P1, 0) LSTM_STEP(P2, 1)
    }
    LSTM_STEP(P0, 0) LSTM_STEP(P1, 1) LSTM_STEP(P2, 0)
#undef LSTM_STEP
#undef XLOAD
#undef PICK
}

// ---------------------------------------------------------------------------
// Final linear: out[100][60] = h[.][2400] @ lin_w[60][2400]^T + lin_b,
// h stored as [75][112][32] fp16 (k = t*32 + hc). One wave per (b,o).
// ---------------------------------------------------------------------------
__global__ __launch_bounds__(256) void linear_out(
    const _Float16* __restrict__ h, const float* __restrict__ lw,
    const float* __restrict__ lb, float* __restrict__ out) {
    int wave = (blockIdx.x * 256 + threadIdx.x) >> 6;
    int l = threadIdx.x & 63;
    if (wave >= 6000) return;
    int b = wave / 60, o = wave - b * 60;
    int hc = l & 31, t0 = l >> 5;
    float acc = 0.f;
    for (int t = t0; t < 75; t += 2)
        acc += (float)h[((size_t)t * 112 + b) * 32 + hc] * lw[(size_t)o * 2400 + t * 32 + hc];
    #pragma unroll
    for (int s = 32; s; s >>= 1) acc += __shfl_xor(acc, s, 64);
    if (l == 0) out[b * 60 + o] = acc + lb[o];
}

// ---------------------------------------------------------------------------
extern "C" void kernel_launch(void* const* d_in, const int* in_sizes, int n_in,
                              void* d_out, int out_size, void* d_ws, size_t ws_size,
                              hipStream_t stream) {
    const float* x = (const float*)d_in[0];
    const float* wih[6];
    const float* whhp[6];
    const float* bih[6];
    const float* bhh[6];
    for (int i = 0; i < 6; ++i) {
        wih[i] = (const float*)d_in[1 + 4 * i];
        whhp[i] = (const float*)d_in[2 + 4 * i];
        bih[i] = (const float*)d_in[3 + 4 * i];
        bhh[i] = (const float*)d_in[4 + 4 * i];
    }
    const float* lw = (const float*)d_in[25];
    const float* lb = (const float*)d_in[26];
    float* out = (float*)d_out;

    char* ws = (char*)d_ws;
    size_t cur = 0;
    auto alloc = [&](size_t b) {
        size_t o = cur;
        cur += (b + 255) & ~(size_t)255;
        return o;
    };
    _Float16* x16 = (_Float16*)(ws + alloc((size_t)8448 * 76 * 2));
    _Float16* wI[6];
    const size_t wihBytes[6] = {77824, 131072, 65536, 32768, 16384, 8192};
    for (int i = 0; i < 6; ++i) wI[i] = (_Float16*)(ws + alloc(wihBytes[i]));
    _Float16* wH[6];
    const size_t whhBytes[6] = {131072, 131072, 32768, 32768, 8192, 8192};
    for (int i = 0; i < 6; ++i) wH[i] = (_Float16*)(ws + alloc(whhBytes[i]));
    float* biasI = (float*)(ws + alloc(1792 * 4));
    float* xg = (float*)(ws + alloc((size_t)78 * 28 * 512 * 4 * 4));  // +3t slack
    _Float16* hA = (_Float16*)(ws + alloc((size_t)8448 * 128 * 2));
    _Float16* hB = (_Float16*)(ws + alloc((size_t)8448 * 128 * 2));

    PrepPtrs pp;
    for (int i = 0; i < 6; ++i) {
        pp.wih[i] = wih[i];
        pp.whh[i] = whhp[i];
        pp.bi[i] = bih[i];
        pp.bh[i] = bhh[i];
        pp.wihI[i] = wI[i];
        pp.whh16[i] = wH[i];
    }
    pp.x = x;
    pp.biasI = biasI;
    pp.x16 = x16;
    prep_kernel<<<3835, 256, 0, stream>>>(pp);

    // layer 0: I=75 (Kv=76), H=128
    gemm_xg<3><<<dim3(150, 8), 256, 0, stream>>>(x16, wI[0], biasI + 0, xg, 76, 512);
    lstm_rec<128><<<25, 512, 0, stream>>>(xg, wH[0], hA);
    // layer 1: I=128, H=128
    gemm_xg<4><<<dim3(150, 8), 256, 0, stream>>>(hA, wI[1], biasI + 512, xg, 128, 512);
    lstm_rec<128><<<25, 512, 0, stream>>>(xg, wH[1], hB);
    // layer 2: I=128, H=64
    gemm_xg<4><<<dim3(150, 4), 256, 0, stream>>>(hB, wI[2], biasI + 1024, xg, 128, 256);
    lstm_rec<64><<<25, 256, 0, stream>>>(xg, wH[2], hA);
    // layer 3: I=64, H=64
    gemm_xg<2><<<dim3(150, 4), 256, 0, stream>>>(hA, wI[3], biasI + 1280, xg, 64, 256);
    lstm_rec<64><<<25, 256, 0, stream>>>(xg, wH[3], hB);
    // layer 4: I=64, H=32
    gemm_xg<2><<<dim3(150, 2), 256, 0, stream>>>(hB, wI[4], biasI + 1536, xg, 64, 128);
    lstm_rec<32><<<25, 128, 0, stream>>>(xg, wH[4], hA);
    // layer 5: I=32, H=32
    gemm_xg<1><<<dim3(150, 2), 256, 0, stream>>>(hA, wI[5], biasI + 1664, xg, 32, 128);
    lstm_rec<32><<<25, 128, 0, stream>>>(xg, wH[5], hB);

    linear_out<<<1500, 256, 0, stream>>>(hB, lw, lb, out);
}